// Round 5
// baseline (100.792 us; speedup 1.0000x reference)
//
#include <hip/hip_runtime.h>

namespace {
constexpr int CIN = 64, COUT = 64, SS = 1024, KK = 3;
constexpr int STL = 4;            // s per block
constexpr int POS = STL + 2;      // 6 halo positions
constexpr int NCG = 8, CPG = 8;   // 8 c-groups of 8 channels (2 per wave)
}

// Grid 512 = 256 s-tiles x 2 o-halves; block 256 threads (4 waves) -> 2 blocks/CU.
// Phase-decorrelation: two independent blocks per CU overlap VMEM phase of one
// with FMA/LDS phase of the other (1 block/CU ran phases in lockstep = serial pipes).
// Thread (sl 0..3, og 0..7 -> 4 o's, cg 0..7 -> 8 c's); all 16 b in registers.
// Weights read exactly once globally (o-partition across blocks). All array
// indices compile-time (R3 lesson: runtime index -> scratch spill).
__global__ __launch_bounds__(256, 2)
void locon1d(const float* __restrict__ in, const float* __restrict__ wt,
             const float* __restrict__ bias, float* __restrict__ out) {
  __shared__ float smem[6144];  // 24 KB: xs (6144 floats); reused as reduce buffer (4096)

  const int tid = threadIdx.x;
  const int sl  = tid & 3;
  const int og  = (tid >> 2) & 7;
  const int cg  = tid >> 5;          // 0..7 (each wave holds 2 cg halves)
  const int bid = blockIdx.x;
  // XCD swizzle: bid%8 = XCD. st, st+1 and both o-halves (bid, bid+256) share an XCD
  // -> weight 48B segments and restaged input merge in that XCD's L2.
  const int oh  = bid >> 8;          // o-half (0/1)
  const int st  = ((bid & 7) << 5) + ((bid >> 3) & 31);
  const int s0  = st * STL;
  const int s   = s0 + sl;
  const int o0  = oh * 32 + og * 4;
  const int cb  = cg * CPG;

  // ---- stage input tile to LDS: xs[c][p][b], 64c x 6pos x 16b (24 KB) ----
  #pragma unroll
  for (int i = 0; i < 6; ++i) {
    const int t  = tid + i * 256;      // 0..1535 = 64c * 6p * 4bq
    const int c  = t / 24;
    const int r  = t - c * 24;
    const int bq = r / 6;
    const int p  = r - bq * 6;
    const int sg = s0 - 1 + p;
    const bool v = (unsigned)sg < (unsigned)SS;
    const float* ip = in + ((size_t)(4 * bq) * CIN + c) * SS + sg;
    float4 x4;
    x4.x = v ? ip[0] : 0.f;
    x4.y = v ? ip[(size_t)1 * CIN * SS] : 0.f;
    x4.z = v ? ip[(size_t)2 * CIN * SS] : 0.f;
    x4.w = v ? ip[(size_t)3 * CIN * SS] : 0.f;
    *reinterpret_cast<float4*>(&smem[(c * POS + p) * 16 + 4 * bq]) = x4;
  }
  __syncthreads();

  // ---- weight preload: all 96 dwords/thread issued here, used far below ----
  float w[CPG][4][KK];   // compile-time indices only
  #pragma unroll
  for (int oo = 0; oo < 4; ++oo) {
    const float* wp = wt + (((size_t)(o0 + oo) * CIN + cb) * SS + s) * KK;
    #pragma unroll
    for (int c = 0; c < CPG; ++c)
      #pragma unroll
      for (int k = 0; k < KK; ++k)
        w[c][oo][k] = wp[(size_t)c * SS * KK + k];
  }

  // ---- compute: 8c x 3k x 16b x 4o FMAs, LDS b128 reads ----
  float acc[4][16];
  #pragma unroll
  for (int oo = 0; oo < 4; ++oo)
    #pragma unroll
    for (int b = 0; b < 16; ++b) acc[oo][b] = 0.f;

  #pragma unroll
  for (int c = 0; c < CPG; ++c) {
    #pragma unroll
    for (int k = 0; k < KK; ++k) {
      const float* base = &smem[((cb + c) * POS + sl + k) * 16];
      #pragma unroll
      for (int g = 0; g < 4; ++g) {
        const float4 x4 = *reinterpret_cast<const float4*>(base + 4 * g);
        #pragma unroll
        for (int oo = 0; oo < 4; ++oo) {
          const float wv = w[c][oo][k];
          acc[oo][4 * g + 0] += wv * x4.x;
          acc[oo][4 * g + 1] += wv * x4.y;
          acc[oo][4 * g + 2] += wv * x4.z;
          acc[oo][4 * g + 3] += wv * x4.w;
        }
      }
    }
  }

  // ---- in-block reduction over cg (8 partials), 4 rounds over oo ----
  // buffer: smem[cg*512 + (b*8+og)*4 + sl]  (4096 floats; aliases dead xs)
  #pragma unroll
  for (int oo = 0; oo < 4; ++oo) {
    __syncthreads();                    // round 0 also guards xs alias
    #pragma unroll
    for (int b = 0; b < 16; ++b)
      smem[cg * 512 + (b * 8 + og) * 4 + sl] = acc[oo][b];
    __syncthreads();
    #pragma unroll
    for (int i = 0; i < 2; ++i) {
      const int item = tid + i * 256;   // 0..511 = (b 0..15, og2 0..7, sl2 0..3)
      float sum = 0.f;
      #pragma unroll
      for (int g = 0; g < NCG; ++g) sum += smem[g * 512 + item];
      const int b   = item >> 5;
      const int rem = item & 31;
      const int o   = oh * 32 + (rem >> 2) * 4 + oo;
      const int s2  = s0 + (rem & 3);
      out[((size_t)b * COUT + o) * SS + s2] = sum + bias[o * SS + s2];
    }
  }
}

extern "C" void kernel_launch(void* const* d_in, const int* in_sizes, int n_in,
                              void* d_out, int out_size, void* d_ws, size_t ws_size,
                              hipStream_t stream) {
  const float* in = (const float*)d_in[0];
  const float* wt = (const float*)d_in[1];
  const float* bs = (const float*)d_in[2];
  float* out = (float*)d_out;
  // 256 s-tiles x 2 o-halves = 512 blocks x 4 waves -> 2 blocks/CU, 8 waves/CU
  hipLaunchKernelGGL(locon1d, dim3(512), dim3(256), 0, stream, in, wt, bs, out);
}